// Round 3
// baseline (623.520 us; speedup 1.0000x reference)
//
#include <hip/hip_runtime.h>

#define T_STEPS 15
#define ROWS_PER_BLOCK 64
#define B_TOTAL 262144
#define LOG2E 1.4426950408889634f

typedef _Float16 half8 __attribute__((ext_vector_type(8)));
typedef _Float16 half4 __attribute__((ext_vector_type(4)));
typedef float f32x4 __attribute__((ext_vector_type(4)));

// Swizzled element index into a [rows][64] fp16 LDS tile (T2 pattern).
__device__ __forceinline__ int swz(int row, int e) {
    return (row * 64 + e) ^ ((row & 7) << 3);
}

__global__ __launch_bounds__(256, 3) void gru_mfma_kernel(
    const float* __restrict__ x,     // (B,15)
    const float* __restrict__ W_ih,  // (192,1)
    const float* __restrict__ W_hh,  // (192,64)
    const float* __restrict__ b_ih,  // (192,)
    const float* __restrict__ b_hh,  // (192,)
    const float* __restrict__ W_fc,  // (2,64)
    const float* __restrict__ b_fc,  // (2,)
    float* __restrict__ out)         // (B,2)
{
    __shared__ _Float16 wlds[192 * 64];                 // 24576 B, exp2-prescaled W_hh^T
    __shared__ float    xlds[ROWS_PER_BLOCK * T_STEPS]; // 3840 B
    __shared__ _Float16 hst[4][2][16 * 64];             // per-wave h hi/lo, 16384 B

    const int tid  = threadIdx.x;
    const int wave = tid >> 6;
    const int lane = tid & 63;
    const int c    = lane & 15;   // N-col / A-row index
    const int g4   = lane >> 4;   // k-slot group / C-row group
    const int r0   = blockIdx.x * ROWS_PER_BLOCK;

    // ---- stage B = W_hh^T, k-permuted by invs(s)=(s&3)*16+(s>>2), exp2-scaled ----
    // r,z rows (n<128) x log2e; n rows x 2*log2e  ->  activations become bare exp2.
    for (int idx = tid; idx < 192 * 64; idx += 256) {
        int n = idx >> 6, s = idx & 63;
        int korig = (s & 3) * 16 + (s >> 2);
        float scale = (n < 128) ? LOG2E : (2.0f * LOG2E);
        wlds[swz(n, s)] = (_Float16)(W_hh[n * 64 + korig] * scale);
    }
    for (int idx = tid; idx < ROWS_PER_BLOCK * T_STEPS; idx += 256)
        xlds[idx] = x[r0 * T_STEPS + idx];
    __syncthreads();

    // ---- per-lane gate constants (jn = tq*16 + c), same exp2 scaling ----
    float wihr[4], wihz[4], wihn[4], seedr[4], seedz[4], seedn[4], bihn[4];
#pragma unroll
    for (int tq = 0; tq < 4; ++tq) {
        int jn = tq * 16 + c;
        wihr[tq]  = W_ih[jn] * LOG2E;
        wihz[tq]  = W_ih[64 + jn] * LOG2E;
        wihn[tq]  = W_ih[128 + jn] * (2.0f * LOG2E);
        seedr[tq] = (b_ih[jn] + b_hh[jn]) * LOG2E;
        seedz[tq] = (b_ih[64 + jn] + b_hh[64 + jn]) * LOG2E;
        seedn[tq] = b_hh[128 + jn] * (2.0f * LOG2E);  // stays inside r*(.) per reference
        bihn[tq]  = b_ih[128 + jn] * (2.0f * LOG2E);
    }

    // ---- loop-invariant LDS addresses ----
    // swz(row, e) with row = tn*16+c: (row&7)==(c&7), and the XOR only touches
    // bits 3..5 of e -> element = tn*1024 + c*64 + (e ^ ((c&7)<<3)).
    const int eS0 = c * 64 + (((g4 * 8) + 0)  ^ ((c & 7) << 3));  // k-step 0
    const int eS1 = c * 64 + (((g4 * 8) + 32) ^ ((c & 7) << 3));  // k-step 1
    const _Float16* bptr0 = &wlds[eS0];
    const _Float16* bptr1 = &wlds[eS1];
    const _Float16* aptr0 = &hst[wave][0][eS0];   // lo buffer = +1024 elements
    const _Float16* aptr1 = &hst[wave][0][eS1];
    _Float16* wr[4];
#pragma unroll
    for (int reg = 0; reg < 4; ++reg) {
        int row = g4 * 4 + reg;
        wr[reg] = &hst[wave][0][row * 64 + ((c * 4) ^ ((row & 7) << 3))];
    }

    f32x4 accr[4], accz[4], accn[4];
#pragma unroll
    for (int tq = 0; tq < 4; ++tq) {
        accr[tq] = (f32x4){seedr[tq], seedr[tq], seedr[tq], seedr[tq]};
        accz[tq] = (f32x4){seedz[tq], seedz[tq], seedz[tq], seedz[tq]};
        accn[tq] = (f32x4){seedn[tq], seedn[tq], seedn[tq], seedn[tq]};
    }

    float h[4][4];  // fp32 h in C layout: (row=g4*4+reg, jn=tq*16+c)
#pragma unroll
    for (int tq = 0; tq < 4; ++tq)
#pragma unroll
        for (int reg = 0; reg < 4; ++reg) h[tq][reg] = 0.0f;

    for (int t = 0; t < T_STEPS; ++t) {
        if (t > 0) {
            half8 Ahi0 = *(const half8*)aptr0;
            half8 Ahi1 = *(const half8*)aptr1;
            half8 Alo0 = *(const half8*)(aptr0 + 1024);
            half8 Alo1 = *(const half8*)(aptr1 + 1024);
#pragma unroll
            for (int tq = 0; tq < 4; ++tq) {
                // B streamed from LDS: base + 16-bit immediate offsets (tn*2048 B)
                half8 Br0 = *(const half8*)(bptr0 + tq * 1024);
                half8 Br1 = *(const half8*)(bptr1 + tq * 1024);
                half8 Bz0 = *(const half8*)(bptr0 + (4 + tq) * 1024);
                half8 Bz1 = *(const half8*)(bptr1 + (4 + tq) * 1024);
                half8 Bn0 = *(const half8*)(bptr0 + (8 + tq) * 1024);
                half8 Bn1 = *(const half8*)(bptr1 + (8 + tq) * 1024);
                accr[tq] = __builtin_amdgcn_mfma_f32_16x16x32_f16(Ahi0, Br0, accr[tq], 0, 0, 0);
                accr[tq] = __builtin_amdgcn_mfma_f32_16x16x32_f16(Ahi1, Br1, accr[tq], 0, 0, 0);
                accz[tq] = __builtin_amdgcn_mfma_f32_16x16x32_f16(Ahi0, Bz0, accz[tq], 0, 0, 0);
                accz[tq] = __builtin_amdgcn_mfma_f32_16x16x32_f16(Ahi1, Bz1, accz[tq], 0, 0, 0);
                accn[tq] = __builtin_amdgcn_mfma_f32_16x16x32_f16(Ahi0, Bn0, accn[tq], 0, 0, 0);
                accn[tq] = __builtin_amdgcn_mfma_f32_16x16x32_f16(Ahi1, Bn1, accn[tq], 0, 0, 0);
                accn[tq] = __builtin_amdgcn_mfma_f32_16x16x32_f16(Alo0, Bn0, accn[tq], 0, 0, 0);
                accn[tq] = __builtin_amdgcn_mfma_f32_16x16x32_f16(Alo1, Bn1, accn[tq], 0, 0, 0);
            }
        }

        float xt[4];
#pragma unroll
        for (int reg = 0; reg < 4; ++reg)
            xt[reg] = xlds[(wave * 16 + g4 * 4 + reg) * T_STEPS + t];

#pragma unroll
        for (int reg = 0; reg < 4; ++reg) {
            half4 vh, vl;
#pragma unroll
            for (int tq = 0; tq < 4; ++tq) {
                float pr = __builtin_fmaf(xt[reg], wihr[tq], accr[tq][reg]);
                float pz = __builtin_fmaf(xt[reg], wihz[tq], accz[tq][reg]);
                float er = __builtin_amdgcn_exp2f(-pr);   // exp(-pr_unscaled)
                float ez = __builtin_amdgcn_exp2f(-pz);
                float rg = __builtin_amdgcn_rcpf(1.0f + er);
                float zg = __builtin_amdgcn_rcpf(1.0f + ez);
                float na = __builtin_fmaf(rg, accn[tq][reg],
                            __builtin_fmaf(xt[reg], wihn[tq], bihn[tq]));  // = 2*log2e*na
                float en = __builtin_amdgcn_exp2f(-na);   // exp(-2*na_unscaled)
                float ng = __builtin_fmaf(2.0f, __builtin_amdgcn_rcpf(1.0f + en), -1.0f);
                float hn = __builtin_fmaf(zg, h[tq][reg] - ng, ng);
                h[tq][reg] = hn;
                _Float16 hi16 = (_Float16)hn;
                vh[tq] = hi16;
                vl[tq] = (_Float16)(hn - (float)hi16);
            }
            *(half4*)wr[reg] = vh;            // s = c*4 + tq, one b64 write
            *(half4*)(wr[reg] + 1024) = vl;
        }
#pragma unroll
        for (int tq = 0; tq < 4; ++tq) {
            accr[tq] = (f32x4){seedr[tq], seedr[tq], seedr[tq], seedr[tq]};
            accz[tq] = (f32x4){seedz[tq], seedz[tq], seedz[tq], seedz[tq]};
            accn[tq] = (f32x4){seedn[tq], seedn[tq], seedn[tq], seedn[tq]};
        }
    }

    // ---- FC head from exact fp32 h; W_fc loaded only here (not loop-live) ----
    float wfc0[4], wfc1[4];
#pragma unroll
    for (int tq = 0; tq < 4; ++tq) {
        wfc0[tq] = W_fc[tq * 16 + c];
        wfc1[tq] = W_fc[64 + tq * 16 + c];
    }
#pragma unroll
    for (int reg = 0; reg < 4; ++reg) {
        float s0 = 0.0f, s1 = 0.0f;
#pragma unroll
        for (int tq = 0; tq < 4; ++tq) {
            s0 = __builtin_fmaf(h[tq][reg], wfc0[tq], s0);
            s1 = __builtin_fmaf(h[tq][reg], wfc1[tq], s1);
        }
#pragma unroll
        for (int m = 1; m < 16; m <<= 1) {
            s0 += __shfl_xor(s0, m, 64);
            s1 += __shfl_xor(s1, m, 64);
        }
        if (c == 0) {
            int gr = r0 + wave * 16 + g4 * 4 + reg;
            out[gr * 2 + 0] = s0 + b_fc[0];
            out[gr * 2 + 1] = s1 + b_fc[1];
        }
    }
}

extern "C" void kernel_launch(void* const* d_in, const int* in_sizes, int n_in,
                              void* d_out, int out_size, void* d_ws, size_t ws_size,
                              hipStream_t stream) {
    const float* x    = (const float*)d_in[0];
    const float* W_ih = (const float*)d_in[1];
    const float* W_hh = (const float*)d_in[2];
    const float* b_ih = (const float*)d_in[3];
    const float* b_hh = (const float*)d_in[4];
    const float* W_fc = (const float*)d_in[5];
    const float* b_fc = (const float*)d_in[6];
    float* out = (float*)d_out;

    dim3 grid(B_TOTAL / ROWS_PER_BLOCK);
    dim3 block(256);
    gru_mfma_kernel<<<grid, block, 0, stream>>>(x, W_ih, W_hh, b_ih, b_hh, W_fc, b_fc, out);
}

// Round 4
// 247.447 us; speedup vs baseline: 2.5198x; 2.5198x over previous
//
#include <hip/hip_runtime.h>

#define T_STEPS 15
#define ROWS_PER_BLOCK 64
#define B_TOTAL 262144
#define LOG2E 1.4426950408889634f

typedef _Float16 half8 __attribute__((ext_vector_type(8)));
typedef _Float16 half4 __attribute__((ext_vector_type(4)));
typedef float f32x4 __attribute__((ext_vector_type(4)));
typedef float f32x4v __attribute__((ext_vector_type(4)));

// Swizzled element index into a [rows][64] fp16 LDS tile (T2 pattern).
__device__ __forceinline__ int swz(int row, int e) {
    return (row * 64 + e) ^ ((row & 7) << 3);
}

__global__ __launch_bounds__(256, 3) void gru_mfma_kernel(
    const float* __restrict__ x,     // (B,15)
    const float* __restrict__ W_ih,  // (192,1)
    const float* __restrict__ W_hh,  // (192,64)
    const float* __restrict__ b_ih,  // (192,)
    const float* __restrict__ b_hh,  // (192,)
    const float* __restrict__ W_fc,  // (2,64)
    const float* __restrict__ b_fc,  // (2,)
    float* __restrict__ out)         // (B,2)
{
    __shared__ _Float16 wlds[192 * 64];                 // 24576 B, exp2-prescaled W_hh^T
    __shared__ float    xlds[T_STEPS * ROWS_PER_BLOCK]; // 3840 B, transposed [t][row]
    __shared__ _Float16 hst[4][2][16 * 64];             // per-wave h hi/lo, 16384 B

    const int tid  = threadIdx.x;
    const int wave = tid >> 6;
    const int lane = tid & 63;
    const int c    = lane & 15;   // N-col / A-row index
    const int g4   = lane >> 4;   // k-slot group / C-row group
    const int r0   = blockIdx.x * ROWS_PER_BLOCK;

    // ---- stage B = W_hh^T, k-permuted by invs(s)=(s&3)*16+(s>>2), exp2-scaled ----
    for (int idx = tid; idx < 192 * 64; idx += 256) {
        int n = idx >> 6, s = idx & 63;
        int korig = (s & 3) * 16 + (s >> 2);
        float scale = (n < 128) ? LOG2E : (2.0f * LOG2E);
        wlds[swz(n, s)] = (_Float16)(W_hh[n * 64 + korig] * scale);
    }
    // x transposed: xlds[t*64 + row] (coalesced global read; one-time LDS scatter)
    for (int idx = tid; idx < ROWS_PER_BLOCK * T_STEPS; idx += 256) {
        int row = idx / T_STEPS, t = idx - row * T_STEPS;
        xlds[t * 64 + row] = x[r0 * T_STEPS + idx];
    }
    __syncthreads();

    // ---- per-lane gate constants (jn = tq*16 + c), exp2-prescaled ----
    float wihr[4], wihz[4], wihn[4], seedr[4], seedz[4], seedn[4], bihn[4];
#pragma unroll
    for (int tq = 0; tq < 4; ++tq) {
        int jn = tq * 16 + c;
        wihr[tq]  = W_ih[jn] * LOG2E;
        wihz[tq]  = W_ih[64 + jn] * LOG2E;
        wihn[tq]  = W_ih[128 + jn] * (2.0f * LOG2E);
        seedr[tq] = (b_ih[jn] + b_hh[jn]) * LOG2E;
        seedz[tq] = (b_ih[64 + jn] + b_hh[64 + jn]) * LOG2E;
        seedn[tq] = b_hh[128 + jn] * (2.0f * LOG2E);  // stays inside r*(.) per reference
        bihn[tq]  = b_ih[128 + jn] * (2.0f * LOG2E);
    }

    // ---- loop-invariant LDS byte offsets (swizzle folded; see round-2 notes) ----
    const int eS0 = c * 64 + (((g4 * 8) + 0)  ^ ((c & 7) << 3));  // k-step 0
    const int eS1 = c * 64 + (((g4 * 8) + 32) ^ ((c & 7) << 3));  // k-step 1
    const int bytesS0 = eS0 * 2;
    const int bytesS1 = eS1 * 2;
    const _Float16* aptr0 = &hst[wave][0][eS0];   // lo buffer = +1024 elements
    const _Float16* aptr1 = &hst[wave][0][eS1];
    _Float16* wr[4];
#pragma unroll
    for (int reg = 0; reg < 4; ++reg) {
        int row = g4 * 4 + reg;
        wr[reg] = &hst[wave][0][row * 64 + ((c * 4) ^ ((row & 7) << 3))];
    }

    f32x4 accr[4], accz[4], accn[4];
#pragma unroll
    for (int tq = 0; tq < 4; ++tq) {
        accr[tq] = (f32x4){seedr[tq], seedr[tq], seedr[tq], seedr[tq]};
        accz[tq] = (f32x4){seedz[tq], seedz[tq], seedz[tq], seedz[tq]};
        accn[tq] = (f32x4){seedn[tq], seedn[tq], seedn[tq], seedn[tq]};
    }

    float h[4][4];  // fp32 h in C layout: (row=g4*4+reg, jn=tq*16+c)
#pragma unroll
    for (int tq = 0; tq < 4; ++tq)
#pragma unroll
        for (int reg = 0; reg < 4; ++reg) h[tq][reg] = 0.0f;

    const char* wbase = (const char*)&wlds[0];

#pragma unroll 1
    for (int t = 0; t < T_STEPS; ++t) {
        if (t > 0) {
            // Launder the B byte-offsets so the 24 B-tile loads CANNOT be
            // LICM-hoisted out of the t-loop (round-3 spill disaster). 32-bit
            // offsets keep LDS addrspace provenance -> still ds_read_b128
            // with folded tn*2048 immediates.
            int ofA = bytesS0, ofB = bytesS1;
            asm volatile("" : "+v"(ofA), "+v"(ofB));
            const char* bp0 = wbase + ofA;
            const char* bp1 = wbase + ofB;

            half8 Ahi0 = *(const half8*)aptr0;
            half8 Ahi1 = *(const half8*)aptr1;
            half8 Alo0 = *(const half8*)(aptr0 + 1024);
            half8 Alo1 = *(const half8*)(aptr1 + 1024);
#pragma unroll
            for (int tq = 0; tq < 4; ++tq) {
                half8 Br0 = *(const half8*)(bp0 + tq * 2048);
                half8 Br1 = *(const half8*)(bp1 + tq * 2048);
                half8 Bz0 = *(const half8*)(bp0 + (4 + tq) * 2048);
                half8 Bz1 = *(const half8*)(bp1 + (4 + tq) * 2048);
                half8 Bn0 = *(const half8*)(bp0 + (8 + tq) * 2048);
                half8 Bn1 = *(const half8*)(bp1 + (8 + tq) * 2048);
                accr[tq] = __builtin_amdgcn_mfma_f32_16x16x32_f16(Ahi0, Br0, accr[tq], 0, 0, 0);
                accr[tq] = __builtin_amdgcn_mfma_f32_16x16x32_f16(Ahi1, Br1, accr[tq], 0, 0, 0);
                accz[tq] = __builtin_amdgcn_mfma_f32_16x16x32_f16(Ahi0, Bz0, accz[tq], 0, 0, 0);
                accz[tq] = __builtin_amdgcn_mfma_f32_16x16x32_f16(Ahi1, Bz1, accz[tq], 0, 0, 0);
                accn[tq] = __builtin_amdgcn_mfma_f32_16x16x32_f16(Ahi0, Bn0, accn[tq], 0, 0, 0);
                accn[tq] = __builtin_amdgcn_mfma_f32_16x16x32_f16(Ahi1, Bn1, accn[tq], 0, 0, 0);
                accn[tq] = __builtin_amdgcn_mfma_f32_16x16x32_f16(Alo0, Bn0, accn[tq], 0, 0, 0);
                accn[tq] = __builtin_amdgcn_mfma_f32_16x16x32_f16(Alo1, Bn1, accn[tq], 0, 0, 0);
                // Fence between tq groups (not after the last): stops the
                // scheduler clustering all 24 B-loads -> bounded reg pressure.
                if (tq < 3) __builtin_amdgcn_sched_barrier(0);
            }
        }

        // one b128: x for this wave's 4 rows at timestep t
        f32x4v xt4 = *(const f32x4v*)&xlds[t * 64 + wave * 16 + g4 * 4];

#pragma unroll
        for (int reg = 0; reg < 4; ++reg) {
            half4 vh, vl;
            float xt = xt4[reg];
#pragma unroll
            for (int tq = 0; tq < 4; ++tq) {
                float pr = __builtin_fmaf(xt, wihr[tq], accr[tq][reg]);
                float pz = __builtin_fmaf(xt, wihz[tq], accz[tq][reg]);
                float er = __builtin_amdgcn_exp2f(-pr);
                float ez = __builtin_amdgcn_exp2f(-pz);
                float rg = __builtin_amdgcn_rcpf(1.0f + er);
                float zg = __builtin_amdgcn_rcpf(1.0f + ez);
                float na = __builtin_fmaf(rg, accn[tq][reg],
                            __builtin_fmaf(xt, wihn[tq], bihn[tq]));
                float en = __builtin_amdgcn_exp2f(-na);
                float ng = __builtin_fmaf(2.0f, __builtin_amdgcn_rcpf(1.0f + en), -1.0f);
                float hn = __builtin_fmaf(zg, h[tq][reg] - ng, ng);
                h[tq][reg] = hn;
                _Float16 hi16 = (_Float16)hn;
                vh[tq] = hi16;
                vl[tq] = (_Float16)(hn - (float)hi16);
            }
            *(half4*)wr[reg] = vh;            // s = c*4 + tq, one b64 write
            *(half4*)(wr[reg] + 1024) = vl;
        }
#pragma unroll
        for (int tq = 0; tq < 4; ++tq) {
            accr[tq] = (f32x4){seedr[tq], seedr[tq], seedr[tq], seedr[tq]};
            accz[tq] = (f32x4){seedz[tq], seedz[tq], seedz[tq], seedz[tq]};
            accn[tq] = (f32x4){seedn[tq], seedn[tq], seedn[tq], seedn[tq]};
        }
    }

    // ---- FC head from exact fp32 h ----
    float wfc0[4], wfc1[4];
#pragma unroll
    for (int tq = 0; tq < 4; ++tq) {
        wfc0[tq] = W_fc[tq * 16 + c];
        wfc1[tq] = W_fc[64 + tq * 16 + c];
    }
#pragma unroll
    for (int reg = 0; reg < 4; ++reg) {
        float s0 = 0.0f, s1 = 0.0f;
#pragma unroll
        for (int tq = 0; tq < 4; ++tq) {
            s0 = __builtin_fmaf(h[tq][reg], wfc0[tq], s0);
            s1 = __builtin_fmaf(h[tq][reg], wfc1[tq], s1);
        }
#pragma unroll
        for (int m = 1; m < 16; m <<= 1) {
            s0 += __shfl_xor(s0, m, 64);
            s1 += __shfl_xor(s1, m, 64);
        }
        if (c == 0) {
            int gr = r0 + wave * 16 + g4 * 4 + reg;
            out[gr * 2 + 0] = s0 + b_fc[0];
            out[gr * 2 + 1] = s1 + b_fc[1];
        }
    }
}

extern "C" void kernel_launch(void* const* d_in, const int* in_sizes, int n_in,
                              void* d_out, int out_size, void* d_ws, size_t ws_size,
                              hipStream_t stream) {
    const float* x    = (const float*)d_in[0];
    const float* W_ih = (const float*)d_in[1];
    const float* W_hh = (const float*)d_in[2];
    const float* b_ih = (const float*)d_in[3];
    const float* b_hh = (const float*)d_in[4];
    const float* W_fc = (const float*)d_in[5];
    const float* b_fc = (const float*)d_in[6];
    float* out = (float*)d_out;

    dim3 grid(B_TOTAL / ROWS_PER_BLOCK);
    dim3 block(256);
    gru_mfma_kernel<<<grid, block, 0, stream>>>(x, W_ih, W_hh, b_ih, b_hh, W_fc, b_fc, out);
}

// Round 6
// 242.574 us; speedup vs baseline: 2.5704x; 1.0201x over previous
//
#include <hip/hip_runtime.h>

#define T_STEPS 15
#define ROWS_PER_BLOCK 64
#define B_TOTAL 262144
#define LOG2E 1.4426950408889634f

typedef _Float16 half8 __attribute__((ext_vector_type(8)));
typedef _Float16 half4 __attribute__((ext_vector_type(4)));
typedef __fp16   fp16x2 __attribute__((ext_vector_type(2)));   // cvt_pkrtz return type
typedef float f32x4 __attribute__((ext_vector_type(4)));

// VGPR-form MFMA (gfx950 unified RF): "v" constraints force C/D into VGPRs,
// eliminating v_accvgpr_read/write traffic (~192 cyc/wave-timestep at AGPR form).
// INIT variant overwrites acc (fresh accumulation, C = shared zero vector);
// "=&v" early-clobber so D cannot alias the zero vector's registers.
#define MFMA_INIT(acc, a, b, z) \
    asm("v_mfma_f32_16x16x32_f16 %0, %1, %2, %3" : "=&v"(acc) : "v"(a), "v"(b), "v"(z))
#define MFMA_ACC(acc, a, b) \
    asm("v_mfma_f32_16x16x32_f16 %0, %1, %2, %0" : "+v"(acc) : "v"(a), "v"(b))

// Swizzled element index into a [rows][64] fp16 LDS tile (T2 pattern).
__device__ __forceinline__ int swz(int row, int e) {
    return (row * 64 + e) ^ ((row & 7) << 3);
}

__global__ __launch_bounds__(256, 3) void gru_mfma_kernel(
    const float* __restrict__ x,     // (B,15)
    const float* __restrict__ W_ih,  // (192,1)
    const float* __restrict__ W_hh,  // (192,64)
    const float* __restrict__ b_ih,  // (192,)
    const float* __restrict__ b_hh,  // (192,)
    const float* __restrict__ W_fc,  // (2,64)
    const float* __restrict__ b_fc,  // (2,)
    float* __restrict__ out)         // (B,2)
{
    __shared__ _Float16 wlds[192 * 64];                 // 24576 B, exp2-prescaled W_hh^T
    __shared__ float    xlds[T_STEPS * ROWS_PER_BLOCK]; // 3840 B, transposed [t][row]
    __shared__ _Float16 hst[4][2][16 * 64];             // per-wave h hi/lo, 16384 B

    const int tid  = threadIdx.x;
    const int wave = tid >> 6;
    const int lane = tid & 63;
    const int c    = lane & 15;   // N-col / A-row index
    const int g4   = lane >> 4;   // k-slot group / C-row group
    const int r0   = blockIdx.x * ROWS_PER_BLOCK;

    // ---- stage B = W_hh^T, k-permuted by invs(s)=(s&3)*16+(s>>2), exp2-scaled ----
    for (int idx = tid; idx < 192 * 64; idx += 256) {
        int n = idx >> 6, s = idx & 63;
        int korig = (s & 3) * 16 + (s >> 2);
        float scale = (n < 128) ? LOG2E : (2.0f * LOG2E);
        wlds[swz(n, s)] = (_Float16)(W_hh[n * 64 + korig] * scale);
    }
    // x transposed: xlds[t*64 + row]
    for (int idx = tid; idx < ROWS_PER_BLOCK * T_STEPS; idx += 256) {
        int row = idx / T_STEPS, t = idx - row * T_STEPS;
        xlds[t * 64 + row] = x[r0 * T_STEPS + idx];
    }
    __syncthreads();

    // ---- per-lane gate constants (jn = tq*16 + c), exp2-prescaled ----
    float wihr[4], wihz[4], wihn[4], seedr[4], seedz[4], seedn[4], bihn[4];
#pragma unroll
    for (int tq = 0; tq < 4; ++tq) {
        int jn = tq * 16 + c;
        wihr[tq]  = W_ih[jn] * LOG2E;
        wihz[tq]  = W_ih[64 + jn] * LOG2E;
        wihn[tq]  = W_ih[128 + jn] * (2.0f * LOG2E);
        seedr[tq] = (b_ih[jn] + b_hh[jn]) * LOG2E;
        seedz[tq] = (b_ih[64 + jn] + b_hh[64 + jn]) * LOG2E;
        seedn[tq] = b_hh[128 + jn] * (2.0f * LOG2E);  // stays inside r*(.) per reference
        bihn[tq]  = b_ih[128 + jn] * (2.0f * LOG2E);
    }

    // ---- loop-invariant LDS byte offsets (swizzle folded) ----
    const int eS0 = c * 64 + (((g4 * 8) + 0)  ^ ((c & 7) << 3));  // k-step 0
    const int eS1 = c * 64 + (((g4 * 8) + 32) ^ ((c & 7) << 3));  // k-step 1
    const int bytesS0 = eS0 * 2;
    const int bytesS1 = eS1 * 2;
    const _Float16* aptr0 = &hst[wave][0][eS0];   // lo buffer = +1024 elements
    const _Float16* aptr1 = &hst[wave][0][eS1];
    _Float16* wr[4];
#pragma unroll
    for (int reg = 0; reg < 4; ++reg) {
        int row = g4 * 4 + reg;
        wr[reg] = &hst[wave][0][row * 64 + ((c * 4) ^ ((row & 7) << 3))];
    }

    const f32x4 zero4 = (f32x4){0.0f, 0.0f, 0.0f, 0.0f};

    f32x4 accr[4], accz[4], accn[4];   // zero only matters for t=0 (t>0 overwritten by MFMA_INIT)
#pragma unroll
    for (int tq = 0; tq < 4; ++tq) {
        accr[tq] = zero4;
        accz[tq] = zero4;
        accn[tq] = zero4;
    }

    float h[4][4];  // fp32 h in C layout: (row=g4*4+reg, jn=tq*16+c)
#pragma unroll
    for (int tq = 0; tq < 4; ++tq)
#pragma unroll
        for (int reg = 0; reg < 4; ++reg) h[tq][reg] = 0.0f;

    const char* wbase = (const char*)&wlds[0];

#pragma unroll 1
    for (int t = 0; t < T_STEPS; ++t) {
        if (t > 0) {
            // Launder B byte-offsets so the 24 B-tile loads cannot be LICM-hoisted
            // (round-3 spill lesson).
            int ofA = bytesS0, ofB = bytesS1;
            asm volatile("" : "+v"(ofA), "+v"(ofB));
            const char* bp0 = wbase + ofA;
            const char* bp1 = wbase + ofB;

            half8 Ahi0 = *(const half8*)aptr0;
            half8 Ahi1 = *(const half8*)aptr1;
            half8 Alo0 = *(const half8*)(aptr0 + 1024);
            half8 Alo1 = *(const half8*)(aptr1 + 1024);
#pragma unroll
            for (int tq = 0; tq < 4; ++tq) {
                half8 Br0 = *(const half8*)(bp0 + tq * 2048);
                half8 Br1 = *(const half8*)(bp1 + tq * 2048);
                half8 Bz0 = *(const half8*)(bp0 + (4 + tq) * 2048);
                half8 Bz1 = *(const half8*)(bp1 + (4 + tq) * 2048);
                half8 Bn0 = *(const half8*)(bp0 + (8 + tq) * 2048);
                half8 Bn1 = *(const half8*)(bp1 + (8 + tq) * 2048);
                MFMA_INIT(accr[tq], Ahi0, Br0, zero4);
                MFMA_ACC (accr[tq], Ahi1, Br1);
                MFMA_INIT(accz[tq], Ahi0, Bz0, zero4);
                MFMA_ACC (accz[tq], Ahi1, Bz1);
                MFMA_INIT(accn[tq], Ahi0, Bn0, zero4);
                MFMA_ACC (accn[tq], Ahi1, Bn1);
                MFMA_ACC (accn[tq], Alo0, Bn0);
                MFMA_ACC (accn[tq], Alo1, Bn1);
                if (tq < 3) __builtin_amdgcn_sched_barrier(0);
            }
            // asm MFMAs are opaque to the hazard recognizer: pin a nop window
            // between the last MFMA writes and the first VALU reads of acc.
            __builtin_amdgcn_sched_barrier(0);
            asm volatile("s_nop 7\n\ts_nop 7");
            __builtin_amdgcn_sched_barrier(0);
        }

        // one b128: x for this wave's 4 rows at timestep t
        f32x4 xt4 = *(const f32x4*)&xlds[t * 64 + wave * 16 + g4 * 4];

#pragma unroll
        for (int reg = 0; reg < 4; ++reg) {
            float xt = xt4[reg];
            float hnv[4];
#pragma unroll
            for (int tq = 0; tq < 4; ++tq) {
                float pr = accr[tq][reg] + __builtin_fmaf(xt, wihr[tq], seedr[tq]);
                float pz = accz[tq][reg] + __builtin_fmaf(xt, wihz[tq], seedz[tq]);
                float er = __builtin_amdgcn_exp2f(-pr);
                float ez = __builtin_amdgcn_exp2f(-pz);
                float rg = __builtin_amdgcn_rcpf(1.0f + er);
                float zg = __builtin_amdgcn_rcpf(1.0f + ez);
                float an = accn[tq][reg] + seedn[tq];
                float na = __builtin_fmaf(rg, an,
                            __builtin_fmaf(xt, wihn[tq], bihn[tq]));
                float en = __builtin_amdgcn_exp2f(-na);
                float ng = __builtin_fmaf(2.0f, __builtin_amdgcn_rcpf(1.0f + en), -1.0f);
                float hn = __builtin_fmaf(zg, h[tq][reg] - ng, ng);
                h[tq][reg] = hn;
                hnv[tq] = hn;
            }
            // packed hi/lo split: RTZ rounding is fine for a hi+lo decomposition
            fp16x2 h01 = __builtin_amdgcn_cvt_pkrtz(hnv[0], hnv[1]);
            fp16x2 h23 = __builtin_amdgcn_cvt_pkrtz(hnv[2], hnv[3]);
            float l0 = hnv[0] - (float)h01[0];
            float l1 = hnv[1] - (float)h01[1];
            float l2 = hnv[2] - (float)h23[0];
            float l3 = hnv[3] - (float)h23[1];
            fp16x2 l01 = __builtin_amdgcn_cvt_pkrtz(l0, l1);
            fp16x2 l23 = __builtin_amdgcn_cvt_pkrtz(l2, l3);
            half4 vh, vl;
            vh[0] = (_Float16)h01[0]; vh[1] = (_Float16)h01[1];
            vh[2] = (_Float16)h23[0]; vh[3] = (_Float16)h23[1];
            vl[0] = (_Float16)l01[0]; vl[1] = (_Float16)l01[1];
            vl[2] = (_Float16)l23[0]; vl[3] = (_Float16)l23[1];
            *(half4*)wr[reg] = vh;            // s = c*4 + tq, one b64 write
            *(half4*)(wr[reg] + 1024) = vl;
        }
    }

    // ---- FC head from exact fp32 h; launder pointers so W_fc/b_fc loads
    // can't be hoisted above the t-loop (would hold 10 regs live) ----
    const float* wfc = W_fc;
    const float* bfc = b_fc;
    asm volatile("" : "+v"(wfc), "+v"(bfc));
    float wfc0[4], wfc1[4];
#pragma unroll
    for (int tq = 0; tq < 4; ++tq) {
        wfc0[tq] = wfc[tq * 16 + c];
        wfc1[tq] = wfc[64 + tq * 16 + c];
    }
#pragma unroll
    for (int reg = 0; reg < 4; ++reg) {
        float s0 = 0.0f, s1 = 0.0f;
#pragma unroll
        for (int tq = 0; tq < 4; ++tq) {
            s0 = __builtin_fmaf(h[tq][reg], wfc0[tq], s0);
            s1 = __builtin_fmaf(h[tq][reg], wfc1[tq], s1);
        }
#pragma unroll
        for (int m = 1; m < 16; m <<= 1) {
            s0 += __shfl_xor(s0, m, 64);
            s1 += __shfl_xor(s1, m, 64);
        }
        if (c == 0) {
            int gr = r0 + wave * 16 + g4 * 4 + reg;
            out[gr * 2 + 0] = s0 + bfc[0];
            out[gr * 2 + 1] = s1 + bfc[1];
        }
    }
}

extern "C" void kernel_launch(void* const* d_in, const int* in_sizes, int n_in,
                              void* d_out, int out_size, void* d_ws, size_t ws_size,
                              hipStream_t stream) {
    const float* x    = (const float*)d_in[0];
    const float* W_ih = (const float*)d_in[1];
    const float* W_hh = (const float*)d_in[2];
    const float* b_ih = (const float*)d_in[3];
    const float* b_hh = (const float*)d_in[4];
    const float* W_fc = (const float*)d_in[5];
    const float* b_fc = (const float*)d_in[6];
    float* out = (float*)d_out;

    dim3 grid(B_TOTAL / ROWS_PER_BLOCK);
    dim3 block(256);
    gru_mfma_kernel<<<grid, block, 0, stream>>>(x, W_ih, W_hh, b_ih, b_hh, W_fc, b_fc, out);
}

// Round 7
// 236.223 us; speedup vs baseline: 2.6395x; 1.0269x over previous
//
#include <hip/hip_runtime.h>

#define T_STEPS 15
#define ROWS_PER_BLOCK 64
#define B_TOTAL 262144
#define LOG2E 1.4426950408889634f

typedef _Float16 half8 __attribute__((ext_vector_type(8)));
typedef _Float16 half4 __attribute__((ext_vector_type(4)));
typedef __fp16   fp16x2 __attribute__((ext_vector_type(2)));   // cvt_pkrtz return type
typedef float f32x4 __attribute__((ext_vector_type(4)));

// VGPR-form MFMA (gfx950 unified RF). INIT overwrites acc with A*B + C where
// C carries the per-gate bias seed (bias folded into the accumulator init —
// saves the per-eval seed adds on the VALU). "=&v" early-clobber so D can't
// alias the C tuple.
#define MFMA_INIT(acc, a, b, cseed) \
    asm("v_mfma_f32_16x16x32_f16 %0, %1, %2, %3" : "=&v"(acc) : "v"(a), "v"(b), "v"(cseed))
#define MFMA_ACC(acc, a, b) \
    asm("v_mfma_f32_16x16x32_f16 %0, %1, %2, %0" : "+v"(acc) : "v"(a), "v"(b))

// Swizzled element index into a [rows][64] fp16 LDS tile (T2 pattern).
__device__ __forceinline__ int swz(int row, int e) {
    return (row * 64 + e) ^ ((row & 7) << 3);
}

__global__ __launch_bounds__(256, 3) void gru_mfma_kernel(
    const float* __restrict__ x,     // (B,15)
    const float* __restrict__ W_ih,  // (192,1)
    const float* __restrict__ W_hh,  // (192,64)
    const float* __restrict__ b_ih,  // (192,)
    const float* __restrict__ b_hh,  // (192,)
    const float* __restrict__ W_fc,  // (2,64)
    const float* __restrict__ b_fc,  // (2,)
    float* __restrict__ out)         // (B,2)
{
    __shared__ _Float16 wlds[192 * 64];                 // 24576 B, exp2-prescaled W_hh^T
    __shared__ float    xlds[T_STEPS * ROWS_PER_BLOCK]; // 3840 B, transposed [t][row]
    __shared__ _Float16 hst[4][2][16 * 64];             // per-wave h hi/lo, 16384 B

    const int tid  = threadIdx.x;
    const int wave = tid >> 6;
    const int lane = tid & 63;
    const int c    = lane & 15;   // N-col / A-row index
    const int g4   = lane >> 4;   // k-slot group / C-row group
    const int r0   = blockIdx.x * ROWS_PER_BLOCK;

    // ---- stage B = W_hh^T, k-permuted by invs(s)=(s&3)*16+(s>>2), exp2-scaled ----
    for (int idx = tid; idx < 192 * 64; idx += 256) {
        int n = idx >> 6, s = idx & 63;
        int korig = (s & 3) * 16 + (s >> 2);
        float scale = (n < 128) ? LOG2E : (2.0f * LOG2E);
        wlds[swz(n, s)] = (_Float16)(W_hh[n * 64 + korig] * scale);
    }
    // x transposed: xlds[t*64 + row]
    for (int idx = tid; idx < ROWS_PER_BLOCK * T_STEPS; idx += 256) {
        int row = idx / T_STEPS, t = idx - row * T_STEPS;
        xlds[t * 64 + row] = x[r0 * T_STEPS + idx];
    }
    __syncthreads();

    // ---- per-lane gate constants (jn = tq*16 + c), exp2-prescaled ----
    float wihr[4], wihz[4], wihn[4], seedn[4], bihn[4];
    f32x4 sr4[4], sz4[4];   // r/z bias seeds, broadcast to f32x4 for MFMA C-operand
#pragma unroll
    for (int tq = 0; tq < 4; ++tq) {
        int jn = tq * 16 + c;
        wihr[tq]  = W_ih[jn] * LOG2E;
        wihz[tq]  = W_ih[64 + jn] * LOG2E;
        wihn[tq]  = W_ih[128 + jn] * (2.0f * LOG2E);
        float sr  = (b_ih[jn] + b_hh[jn]) * LOG2E;
        float sz  = (b_ih[64 + jn] + b_hh[64 + jn]) * LOG2E;
        sr4[tq] = (f32x4){sr, sr, sr, sr};
        sz4[tq] = (f32x4){sz, sz, sz, sz};
        seedn[tq] = b_hh[128 + jn] * (2.0f * LOG2E);  // stays inside r*(.) per reference
        bihn[tq]  = b_ih[128 + jn] * (2.0f * LOG2E);
    }

    // ---- loop-invariant LDS byte offsets (swizzle folded) ----
    const int eS0 = c * 64 + (((g4 * 8) + 0)  ^ ((c & 7) << 3));  // k-step 0
    const int eS1 = c * 64 + (((g4 * 8) + 32) ^ ((c & 7) << 3));  // k-step 1
    const int bytesS0 = eS0 * 2;
    const int bytesS1 = eS1 * 2;
    const _Float16* aptr0 = &hst[wave][0][eS0];   // lo buffer = +1024 elements
    const _Float16* aptr1 = &hst[wave][0][eS1];
    _Float16* wr[4];
#pragma unroll
    for (int reg = 0; reg < 4; ++reg) {
        int row = g4 * 4 + reg;
        wr[reg] = &hst[wave][0][row * 64 + ((c * 4) ^ ((row & 7) << 3))];
    }

    const f32x4 zero4 = (f32x4){0.0f, 0.0f, 0.0f, 0.0f};

    // t=0: no MFMA -> acc must carry exactly the bias seeds (h=0).
    f32x4 accr[4], accz[4], accn[4];
#pragma unroll
    for (int tq = 0; tq < 4; ++tq) {
        accr[tq] = sr4[tq];
        accz[tq] = sz4[tq];
        accn[tq] = zero4;     // n-seed applied via rg*seedn fma in the gate
    }

    float h[4][4];  // fp32 h in C layout: (row=g4*4+reg, jn=tq*16+c)
#pragma unroll
    for (int tq = 0; tq < 4; ++tq)
#pragma unroll
        for (int reg = 0; reg < 4; ++reg) h[tq][reg] = 0.0f;

    const char* wbase = (const char*)&wlds[0];

#pragma unroll 1
    for (int t = 0; t < T_STEPS; ++t) {
        if (t > 0) {
            // Launder B byte-offsets so the 24 B-tile loads cannot be LICM-hoisted
            // (round-3 spill lesson).
            int ofA = bytesS0, ofB = bytesS1;
            asm volatile("" : "+v"(ofA), "+v"(ofB));
            const char* bp0 = wbase + ofA;
            const char* bp1 = wbase + ofB;

            half8 Ahi0 = *(const half8*)aptr0;
            half8 Ahi1 = *(const half8*)aptr1;
            half8 Alo0 = *(const half8*)(aptr0 + 1024);
            half8 Alo1 = *(const half8*)(aptr1 + 1024);
#pragma unroll
            for (int tq = 0; tq < 4; ++tq) {
                half8 Br0 = *(const half8*)(bp0 + tq * 2048);
                half8 Br1 = *(const half8*)(bp1 + tq * 2048);
                half8 Bz0 = *(const half8*)(bp0 + (4 + tq) * 2048);
                half8 Bz1 = *(const half8*)(bp1 + (4 + tq) * 2048);
                half8 Bn0 = *(const half8*)(bp0 + (8 + tq) * 2048);
                half8 Bn1 = *(const half8*)(bp1 + (8 + tq) * 2048);
                MFMA_INIT(accr[tq], Ahi0, Br0, sr4[tq]);
                MFMA_ACC (accr[tq], Ahi1, Br1);
                MFMA_INIT(accz[tq], Ahi0, Bz0, sz4[tq]);
                MFMA_ACC (accz[tq], Ahi1, Bz1);
                MFMA_INIT(accn[tq], Ahi0, Bn0, zero4);
                MFMA_ACC (accn[tq], Ahi1, Bn1);
                MFMA_ACC (accn[tq], Alo0, Bn0);
                MFMA_ACC (accn[tq], Alo1, Bn1);
                if (tq < 3) __builtin_amdgcn_sched_barrier(0);
            }
            // asm MFMAs are opaque to the hazard recognizer: pin a nop window
            // between the last MFMA writes and the first VALU reads of acc.
            __builtin_amdgcn_sched_barrier(0);
            asm volatile("s_nop 7\n\ts_nop 7");
            __builtin_amdgcn_sched_barrier(0);
        }

        // one b128: x for this wave's 4 rows at timestep t
        f32x4 xt4 = *(const f32x4*)&xlds[t * 64 + wave * 16 + g4 * 4];

#pragma unroll
        for (int reg = 0; reg < 4; ++reg) {
            float xt = xt4[reg];
            float hnv[4];
#pragma unroll
            for (int tq = 0; tq < 4; ++tq) {
                // r-gate: needs its own rcp (feeds the n pre-activation nonlinearly)
                float pr = __builtin_fmaf(xt, wihr[tq], accr[tq][reg]);
                float er = __builtin_amdgcn_exp2f(-pr);
                float rg = __builtin_amdgcn_rcpf(1.0f + er);
                // z and n share ONE rcp via the merged update:
                //   h' = [h*(1+EN) + EZ*(1-EN)] / [(1+EN)*(1+EZ)]
                float pz = __builtin_fmaf(xt, wihz[tq], accz[tq][reg]);
                float ez = __builtin_amdgcn_exp2f(-pz);
                float na2 = __builtin_fmaf(rg, seedn[tq],
                             __builtin_fmaf(xt, wihn[tq], bihn[tq]));
                float na  = __builtin_fmaf(rg, accn[tq][reg], na2);
                float en = __builtin_amdgcn_exp2f(-na);        // e^{-2*pn}
                float A  = 1.0f + en;
                float Cc = 1.0f + ez;
                float D  = A * Cc;
                float R  = __builtin_amdgcn_rcpf(D);
                float P  = __builtin_fmaf(-en, ez, ez);        // EZ*(1-EN)
                float num = __builtin_fmaf(h[tq][reg], A, P);
                float hn = num * R;
                h[tq][reg] = hn;
                hnv[tq] = hn;
            }
            // packed hi/lo split: RTZ rounding is fine for a hi+lo decomposition
            fp16x2 h01 = __builtin_amdgcn_cvt_pkrtz(hnv[0], hnv[1]);
            fp16x2 h23 = __builtin_amdgcn_cvt_pkrtz(hnv[2], hnv[3]);
            float l0 = hnv[0] - (float)h01[0];
            float l1 = hnv[1] - (float)h01[1];
            float l2 = hnv[2] - (float)h23[0];
            float l3 = hnv[3] - (float)h23[1];
            fp16x2 l01 = __builtin_amdgcn_cvt_pkrtz(l0, l1);
            fp16x2 l23 = __builtin_amdgcn_cvt_pkrtz(l2, l3);
            half4 vh, vl;
            vh[0] = (_Float16)h01[0]; vh[1] = (_Float16)h01[1];
            vh[2] = (_Float16)h23[0]; vh[3] = (_Float16)h23[1];
            vl[0] = (_Float16)l01[0]; vl[1] = (_Float16)l01[1];
            vl[2] = (_Float16)l23[0]; vl[3] = (_Float16)l23[1];
            *(half4*)wr[reg] = vh;            // s = c*4 + tq, one b64 write
            *(half4*)(wr[reg] + 1024) = vl;
        }
    }

    // ---- FC head from exact fp32 h; launder pointers so W_fc/b_fc loads
    // can't be hoisted above the t-loop (would hold 10 regs live) ----
    const float* wfc = W_fc;
    const float* bfc = b_fc;
    asm volatile("" : "+v"(wfc), "+v"(bfc));
    float wfc0[4], wfc1[4];
#pragma unroll
    for (int tq = 0; tq < 4; ++tq) {
        wfc0[tq] = wfc[tq * 16 + c];
        wfc1[tq] = wfc[64 + tq * 16 + c];
    }
#pragma unroll
    for (int reg = 0; reg < 4; ++reg) {
        float s0 = 0.0f, s1 = 0.0f;
#pragma unroll
        for (int tq = 0; tq < 4; ++tq) {
            s0 = __builtin_fmaf(h[tq][reg], wfc0[tq], s0);
            s1 = __builtin_fmaf(h[tq][reg], wfc1[tq], s1);
        }
#pragma unroll
        for (int m = 1; m < 16; m <<= 1) {
            s0 += __shfl_xor(s0, m, 64);
            s1 += __shfl_xor(s1, m, 64);
        }
        if (c == 0) {
            int gr = r0 + wave * 16 + g4 * 4 + reg;
            out[gr * 2 + 0] = s0 + bfc[0];
            out[gr * 2 + 1] = s1 + bfc[1];
        }
    }
}

extern "C" void kernel_launch(void* const* d_in, const int* in_sizes, int n_in,
                              void* d_out, int out_size, void* d_ws, size_t ws_size,
                              hipStream_t stream) {
    const float* x    = (const float*)d_in[0];
    const float* W_ih = (const float*)d_in[1];
    const float* W_hh = (const float*)d_in[2];
    const float* b_ih = (const float*)d_in[3];
    const float* b_hh = (const float*)d_in[4];
    const float* W_fc = (const float*)d_in[5];
    const float* b_fc = (const float*)d_in[6];
    float* out = (float*)d_out;

    dim3 grid(B_TOTAL / ROWS_PER_BLOCK);
    dim3 block(256);
    gru_mfma_kernel<<<grid, block, 0, stream>>>(x, W_ih, W_hh, b_ih, b_hh, W_fc, b_fc, out);
}

// Round 8
// 215.934 us; speedup vs baseline: 2.8876x; 1.0940x over previous
//
#include <hip/hip_runtime.h>

#define T_STEPS 15
#define ROWS_PER_BLOCK 128
#define B_TOTAL 262144
#define LOG2E 1.4426950408889634f

typedef _Float16 half8 __attribute__((ext_vector_type(8)));
typedef _Float16 half4 __attribute__((ext_vector_type(4)));
typedef __fp16   fp16x2 __attribute__((ext_vector_type(2)));   // cvt_pkrtz return type
typedef float f32x4 __attribute__((ext_vector_type(4)));

// VGPR-form MFMA (gfx950 unified RF). INIT overwrites acc (C = shared zero
// tuple); "=&v" early-clobber so D can't alias C.
#define MFMA_INIT(acc, a, b, cz) \
    asm("v_mfma_f32_16x16x32_f16 %0, %1, %2, %3" : "=&v"(acc) : "v"(a), "v"(b), "v"(cz))
#define MFMA_ACC(acc, a, b) \
    asm("v_mfma_f32_16x16x32_f16 %0, %1, %2, %0" : "+v"(acc) : "v"(a), "v"(b))

// Swizzled element index into a [rows][64] fp16 LDS tile (T2 pattern).
__device__ __forceinline__ int swz(int row, int e) {
    return (row * 64 + e) ^ ((row & 7) << 3);
}

__global__ __launch_bounds__(256, 2) void gru_mfma_kernel(
    const float* __restrict__ x,     // (B,15)
    const float* __restrict__ W_ih,  // (192,1)
    const float* __restrict__ W_hh,  // (192,64)
    const float* __restrict__ b_ih,  // (192,)
    const float* __restrict__ b_hh,  // (192,)
    const float* __restrict__ W_fc,  // (2,64)
    const float* __restrict__ b_fc,  // (2,)
    float* __restrict__ out)         // (B,2)
{
    __shared__ _Float16 wlds[192 * 64];                 // 24576 B, exp2-prescaled W_hh^T
    __shared__ float    xlds[T_STEPS * ROWS_PER_BLOCK]; // 7680 B, [t][row]
    __shared__ _Float16 hst[8][16 * 64];                // [wave*2+stream], 16384 B

    const int tid  = threadIdx.x;
    const int wave = tid >> 6;
    const int lane = tid & 63;
    const int c    = lane & 15;   // N-col / A-row index
    const int g4   = lane >> 4;   // k-slot group / C-row group
    const int r0   = blockIdx.x * ROWS_PER_BLOCK;

    // ---- stage B = W_hh^T, k-permuted by invs(s)=(s&3)*16+(s>>2), exp2-scaled ----
    for (int idx = tid; idx < 192 * 64; idx += 256) {
        int n = idx >> 6, s = idx & 63;
        int korig = (s & 3) * 16 + (s >> 2);
        float scale = (n < 128) ? LOG2E : (2.0f * LOG2E);
        wlds[swz(n, s)] = (_Float16)(W_hh[n * 64 + korig] * scale);
    }
    // x transposed: xlds[t*128 + row]
    for (int idx = tid; idx < ROWS_PER_BLOCK * T_STEPS; idx += 256) {
        int row = idx / T_STEPS, t = idx - row * T_STEPS;
        xlds[t * ROWS_PER_BLOCK + row] = x[r0 * T_STEPS + idx];
    }
    __syncthreads();

    // ---- per-lane gate constants (jn = tq*16 + c), exp2-prescaled ----
    float wihr[4], wihz[4], wihn[4], sr[4], sz[4], seedn[4], bihn[4];
#pragma unroll
    for (int tq = 0; tq < 4; ++tq) {
        int jn = tq * 16 + c;
        wihr[tq]  = W_ih[jn] * LOG2E;
        wihz[tq]  = W_ih[64 + jn] * LOG2E;
        wihn[tq]  = W_ih[128 + jn] * (2.0f * LOG2E);
        sr[tq]    = (b_ih[jn] + b_hh[jn]) * LOG2E;
        sz[tq]    = (b_ih[64 + jn] + b_hh[64 + jn]) * LOG2E;
        seedn[tq] = b_hh[128 + jn] * (2.0f * LOG2E);  // stays inside r*(.) per reference
        bihn[tq]  = b_ih[128 + jn] * (2.0f * LOG2E);
    }

    // ---- loop-invariant LDS offsets (swizzle folded) ----
    const int eS0 = c * 64 + (((g4 * 8) + 0)  ^ ((c & 7) << 3));  // k-step 0
    const int eS1 = c * 64 + (((g4 * 8) + 32) ^ ((c & 7) << 3));  // k-step 1
    const int bytesS0 = eS0 * 2;
    const int bytesS1 = eS1 * 2;
    const _Float16* aA0 = &hst[wave * 2 + 0][eS0];
    const _Float16* aA1 = &hst[wave * 2 + 0][eS1];
    const _Float16* aB0 = &hst[wave * 2 + 1][eS0];
    const _Float16* aB1 = &hst[wave * 2 + 1][eS1];
    _Float16* wr[2][4];
#pragma unroll
    for (int s = 0; s < 2; ++s)
#pragma unroll
        for (int reg = 0; reg < 4; ++reg) {
            int row = g4 * 4 + reg;
            wr[s][reg] = &hst[wave * 2 + s][row * 64 + ((c * 4) ^ ((row & 7) << 3))];
        }

    const f32x4 zero4 = (f32x4){0.0f, 0.0f, 0.0f, 0.0f};

    f32x4 accr[2][4], accz[2][4], accn[2][4];   // t=0 path needs zeros
#pragma unroll
    for (int s = 0; s < 2; ++s)
#pragma unroll
        for (int tq = 0; tq < 4; ++tq) {
            accr[s][tq] = zero4;
            accz[s][tq] = zero4;
            accn[s][tq] = zero4;
        }

    float h[2][4][4];  // fp32 h, C layout per stream
#pragma unroll
    for (int s = 0; s < 2; ++s)
#pragma unroll
        for (int tq = 0; tq < 4; ++tq)
#pragma unroll
            for (int reg = 0; reg < 4; ++reg) h[s][tq][reg] = 0.0f;

    const char* wbase = (const char*)&wlds[0];

#pragma unroll 1
    for (int t = 0; t < T_STEPS; ++t) {
        if (t > 0) {
            // Launder B byte-offsets so the B-tile loads cannot be LICM-hoisted
            // (round-3 spill lesson).
            int ofA = bytesS0, ofB = bytesS1;
            asm volatile("" : "+v"(ofA), "+v"(ofB));
            const char* bp0 = wbase + ofA;
            const char* bp1 = wbase + ofB;

            half8 A0sA = *(const half8*)aA0;
            half8 A1sA = *(const half8*)aA1;
            half8 A0sB = *(const half8*)aB0;
            half8 A1sB = *(const half8*)aB1;
#pragma unroll
            for (int tq = 0; tq < 4; ++tq) {
                half8 Br0 = *(const half8*)(bp0 + tq * 2048);
                half8 Br1 = *(const half8*)(bp1 + tq * 2048);
                half8 Bz0 = *(const half8*)(bp0 + (4 + tq) * 2048);
                half8 Bz1 = *(const half8*)(bp1 + (4 + tq) * 2048);
                half8 Bn0 = *(const half8*)(bp0 + (8 + tq) * 2048);
                half8 Bn1 = *(const half8*)(bp1 + (8 + tq) * 2048);
                // B-frags feed BOTH streams (12 MFMAs per 6 loads)
                MFMA_INIT(accr[0][tq], A0sA, Br0, zero4);
                MFMA_ACC (accr[0][tq], A1sA, Br1);
                MFMA_INIT(accz[0][tq], A0sA, Bz0, zero4);
                MFMA_ACC (accz[0][tq], A1sA, Bz1);
                MFMA_INIT(accn[0][tq], A0sA, Bn0, zero4);
                MFMA_ACC (accn[0][tq], A1sA, Bn1);
                MFMA_INIT(accr[1][tq], A0sB, Br0, zero4);
                MFMA_ACC (accr[1][tq], A1sB, Br1);
                MFMA_INIT(accz[1][tq], A0sB, Bz0, zero4);
                MFMA_ACC (accz[1][tq], A1sB, Bz1);
                MFMA_INIT(accn[1][tq], A0sB, Bn0, zero4);
                MFMA_ACC (accn[1][tq], A1sB, Bn1);
                if (tq < 3) __builtin_amdgcn_sched_barrier(0);
            }
            // asm MFMAs are opaque to the hazard recognizer: pin a nop window
            // before the first VALU reads of acc.
            __builtin_amdgcn_sched_barrier(0);
            asm volatile("s_nop 7\n\ts_nop 7");
            __builtin_amdgcn_sched_barrier(0);
        }

#pragma unroll
        for (int s = 0; s < 2; ++s) {
            f32x4 xt4 = *(const f32x4*)&xlds[t * ROWS_PER_BLOCK + wave * 32 + s * 16 + g4 * 4];
#pragma unroll
            for (int reg = 0; reg < 4; ++reg) {
                float xt = xt4[reg];
                float hnv[4];
#pragma unroll
                for (int tq = 0; tq < 4; ++tq) {
                    // r-gate: own exp+rcp (feeds n pre-activation nonlinearly)
                    float pr = accr[s][tq][reg] + __builtin_fmaf(xt, wihr[tq], sr[tq]);
                    float er = __builtin_amdgcn_exp2f(-pr);
                    float rg = __builtin_amdgcn_rcpf(1.0f + er);
                    // z and n share ONE rcp via merged update:
                    //   h' = [h*(1+EN) + EZ*(1-EN)] / [(1+EN)*(1+EZ)]
                    float pz = accz[s][tq][reg] + __builtin_fmaf(xt, wihz[tq], sz[tq]);
                    float ez = __builtin_amdgcn_exp2f(-pz);
                    float na = __builtin_fmaf(rg, accn[s][tq][reg],
                                __builtin_fmaf(rg, seedn[tq],
                                 __builtin_fmaf(xt, wihn[tq], bihn[tq])));
                    float en = __builtin_amdgcn_exp2f(-na);     // e^{-2*pn}
                    float A  = 1.0f + en;
                    float Cc = 1.0f + ez;
                    float D  = A * Cc;
                    float R  = __builtin_amdgcn_rcpf(D);
                    float P  = __builtin_fmaf(-en, ez, ez);     // EZ*(1-EN)
                    float num = __builtin_fmaf(h[s][tq][reg], A, P);
                    float hn = num * R;
                    h[s][tq][reg] = hn;
                    hnv[tq] = hn;
                }
                fp16x2 h01 = __builtin_amdgcn_cvt_pkrtz(hnv[0], hnv[1]);
                fp16x2 h23 = __builtin_amdgcn_cvt_pkrtz(hnv[2], hnv[3]);
                half4 vh;
                vh[0] = (_Float16)h01[0]; vh[1] = (_Float16)h01[1];
                vh[2] = (_Float16)h23[0]; vh[3] = (_Float16)h23[1];
                *(half4*)wr[s][reg] = vh;   // s-slot = c*4+tq, one b64 write
            }
        }
    }

    // ---- FC head from exact fp32 h; launder pointers so W_fc/b_fc loads
    // can't be hoisted above the t-loop ----
    const float* wfc = W_fc;
    const float* bfc = b_fc;
    asm volatile("" : "+v"(wfc), "+v"(bfc));
    float wfc0[4], wfc1[4];
#pragma unroll
    for (int tq = 0; tq < 4; ++tq) {
        wfc0[tq] = wfc[tq * 16 + c];
        wfc1[tq] = wfc[64 + tq * 16 + c];
    }
#pragma unroll
    for (int s = 0; s < 2; ++s)
#pragma unroll
    for (int reg = 0; reg < 4; ++reg) {
        float s0 = 0.0f, s1 = 0.0f;
#pragma unroll
        for (int tq = 0; tq < 4; ++tq) {
            s0 = __builtin_fmaf(h[s][tq][reg], wfc0[tq], s0);
            s1 = __builtin_fmaf(h[s][tq][reg], wfc1[tq], s1);
        }
#pragma unroll
        for (int m = 1; m < 16; m <<= 1) {
            s0 += __shfl_xor(s0, m, 64);
            s1 += __shfl_xor(s1, m, 64);
        }
        if (c == 0) {
            int gr = r0 + wave * 32 + s * 16 + g4 * 4 + reg;
            out[gr * 2 + 0] = s0 + bfc[0];
            out[gr * 2 + 1] = s1 + bfc[1];
        }
    }
}

extern "C" void kernel_launch(void* const* d_in, const int* in_sizes, int n_in,
                              void* d_out, int out_size, void* d_ws, size_t ws_size,
                              hipStream_t stream) {
    const float* x    = (const float*)d_in[0];
    const float* W_ih = (const float*)d_in[1];
    const float* W_hh = (const float*)d_in[2];
    const float* b_ih = (const float*)d_in[3];
    const float* b_hh = (const float*)d_in[4];
    const float* W_fc = (const float*)d_in[5];
    const float* b_fc = (const float*)d_in[6];
    float* out = (float*)d_out;

    dim3 grid(B_TOTAL / ROWS_PER_BLOCK);
    dim3 block(256);
    gru_mfma_kernel<<<grid, block, 0, stream>>>(x, W_ih, W_hh, b_ih, b_hh, W_fc, b_fc, out);
}

// Round 9
// 208.533 us; speedup vs baseline: 2.9900x; 1.0355x over previous
//
#include <hip/hip_runtime.h>

#define T_STEPS 15
#define ROWS_PER_BLOCK 128
#define B_TOTAL 262144
#define LOG2E 1.4426950408889634f

typedef _Float16 half8 __attribute__((ext_vector_type(8)));
typedef _Float16 half4 __attribute__((ext_vector_type(4)));
typedef __fp16   fp16x2 __attribute__((ext_vector_type(2)));   // cvt_pkrtz return type
typedef float f32x4 __attribute__((ext_vector_type(4)));

// VGPR-form MFMA (gfx950 unified RF). INIT overwrites acc (C = shared zero
// tuple); "=&v" early-clobber so D can't alias C.
#define MFMA_INIT(acc, a, b, cz) \
    asm("v_mfma_f32_16x16x32_f16 %0, %1, %2, %3" : "=&v"(acc) : "v"(a), "v"(b), "v"(cz))
#define MFMA_ACC(acc, a, b) \
    asm("v_mfma_f32_16x16x32_f16 %0, %1, %2, %0" : "+v"(acc) : "v"(a), "v"(b))

// Swizzled element index into a [rows][64] fp16 LDS tile (T2 pattern).
__device__ __forceinline__ int swz(int row, int e) {
    return (row * 64 + e) ^ ((row & 7) << 3);
}

// One stream's full K=64 matvec block: 26 ds_read_b128 + 24 MFMAs.
// B byte-offsets laundered per invocation so the B-tile loads can't be
// LICM-hoisted (round-3 spill lesson).
#define MFMA_BLOCK(S, AP0, AP1)  do { \
    int ofA = bytesS0, ofB = bytesS1; \
    asm volatile("" : "+v"(ofA), "+v"(ofB)); \
    const char* bp0 = wbase + ofA; \
    const char* bp1 = wbase + ofB; \
    half8 A0 = *(const half8*)(AP0); \
    half8 A1 = *(const half8*)(AP1); \
    _Pragma("unroll") \
    for (int tq = 0; tq < 4; ++tq) { \
        half8 Br0 = *(const half8*)(bp0 + tq * 2048); \
        half8 Br1 = *(const half8*)(bp1 + tq * 2048); \
        half8 Bz0 = *(const half8*)(bp0 + (4 + tq) * 2048); \
        half8 Bz1 = *(const half8*)(bp1 + (4 + tq) * 2048); \
        half8 Bn0 = *(const half8*)(bp0 + (8 + tq) * 2048); \
        half8 Bn1 = *(const half8*)(bp1 + (8 + tq) * 2048); \
        MFMA_INIT(accr[S][tq], A0, Br0, zero4); \
        MFMA_ACC (accr[S][tq], A1, Br1); \
        MFMA_INIT(accz[S][tq], A0, Bz0, zero4); \
        MFMA_ACC (accz[S][tq], A1, Bz1); \
        MFMA_INIT(accn[S][tq], A0, Bn0, zero4); \
        MFMA_ACC (accn[S][tq], A1, Bn1); \
        if (tq < 3) __builtin_amdgcn_sched_barrier(0); \
    } \
} while (0)

// Phase fence + tiny hazard pad (acc writes are >1000 cyc upstream in
// program order; the pad is insurance, not the mechanism).
#define HAZPAD() do { \
    __builtin_amdgcn_sched_barrier(0); \
    asm volatile("s_nop 7"); \
    __builtin_amdgcn_sched_barrier(0); \
} while (0)

// One stream's 16 gate evaluations (5 trans each) + f16 h writeback.
#define GATES(S, TT) do { \
    f32x4 xt4 = *(const f32x4*)&xlds[(TT) * ROWS_PER_BLOCK + wave * 32 + (S) * 16 + g4 * 4]; \
    _Pragma("unroll") \
    for (int reg = 0; reg < 4; ++reg) { \
        float xt = xt4[reg]; \
        float hnv[4]; \
        _Pragma("unroll") \
        for (int tq = 0; tq < 4; ++tq) { \
            float pr = accr[S][tq][reg] + __builtin_fmaf(xt, wihr[tq], sr[tq]); \
            float er = __builtin_amdgcn_exp2f(-pr); \
            float rg = __builtin_amdgcn_rcpf(1.0f + er); \
            float pz = accz[S][tq][reg] + __builtin_fmaf(xt, wihz[tq], sz[tq]); \
            float ez = __builtin_amdgcn_exp2f(-pz); \
            float na = __builtin_fmaf(rg, accn[S][tq][reg], \
                        __builtin_fmaf(rg, seedn[tq], \
                         __builtin_fmaf(xt, wihn[tq], bihn[tq]))); \
            float en = __builtin_amdgcn_exp2f(-na); \
            float A_ = 1.0f + en; \
            float C_ = 1.0f + ez; \
            float R_ = __builtin_amdgcn_rcpf(A_ * C_); \
            float P_ = __builtin_fmaf(-en, ez, ez); \
            float hn = __builtin_fmaf(h[S][tq][reg], A_, P_) * R_; \
            h[S][tq][reg] = hn; \
            hnv[tq] = hn; \
        } \
        fp16x2 h01 = __builtin_amdgcn_cvt_pkrtz(hnv[0], hnv[1]); \
        fp16x2 h23 = __builtin_amdgcn_cvt_pkrtz(hnv[2], hnv[3]); \
        half4 vh; \
        vh[0] = (_Float16)h01[0]; vh[1] = (_Float16)h01[1]; \
        vh[2] = (_Float16)h23[0]; vh[3] = (_Float16)h23[1]; \
        *(half4*)wr[S][reg] = vh; \
    } \
} while (0)

__global__ __launch_bounds__(256, 2) void gru_mfma_kernel(
    const float* __restrict__ x,     // (B,15)
    const float* __restrict__ W_ih,  // (192,1)
    const float* __restrict__ W_hh,  // (192,64)
    const float* __restrict__ b_ih,  // (192,)
    const float* __restrict__ b_hh,  // (192,)
    const float* __restrict__ W_fc,  // (2,64)
    const float* __restrict__ b_fc,  // (2,)
    float* __restrict__ out)         // (B,2)
{
    __shared__ _Float16 wlds[192 * 64];                 // 24576 B, exp2-prescaled W_hh^T
    __shared__ float    xlds[T_STEPS * ROWS_PER_BLOCK]; // 7680 B, [t][row]
    __shared__ _Float16 hst[8][16 * 64];                // [wave*2+stream], 16384 B

    const int tid  = threadIdx.x;
    const int wave = tid >> 6;
    const int lane = tid & 63;
    const int c    = lane & 15;   // N-col / A-row index
    const int g4   = lane >> 4;   // k-slot group / C-row group
    const int r0   = blockIdx.x * ROWS_PER_BLOCK;

    // ---- stage B = W_hh^T, k-permuted by invs(s)=(s&3)*16+(s>>2), exp2-scaled ----
    for (int idx = tid; idx < 192 * 64; idx += 256) {
        int n = idx >> 6, s = idx & 63;
        int korig = (s & 3) * 16 + (s >> 2);
        float scale = (n < 128) ? LOG2E : (2.0f * LOG2E);
        wlds[swz(n, s)] = (_Float16)(W_hh[n * 64 + korig] * scale);
    }
    // x transposed: xlds[t*128 + row]
    for (int idx = tid; idx < ROWS_PER_BLOCK * T_STEPS; idx += 256) {
        int row = idx / T_STEPS, t = idx - row * T_STEPS;
        xlds[t * ROWS_PER_BLOCK + row] = x[r0 * T_STEPS + idx];
    }
    __syncthreads();

    // ---- per-lane gate constants (jn = tq*16 + c), exp2-prescaled ----
    float wihr[4], wihz[4], wihn[4], sr[4], sz[4], seedn[4], bihn[4];
#pragma unroll
    for (int tq = 0; tq < 4; ++tq) {
        int jn = tq * 16 + c;
        wihr[tq]  = W_ih[jn] * LOG2E;
        wihz[tq]  = W_ih[64 + jn] * LOG2E;
        wihn[tq]  = W_ih[128 + jn] * (2.0f * LOG2E);
        sr[tq]    = (b_ih[jn] + b_hh[jn]) * LOG2E;
        sz[tq]    = (b_ih[64 + jn] + b_hh[64 + jn]) * LOG2E;
        seedn[tq] = b_hh[128 + jn] * (2.0f * LOG2E);  // stays inside r*(.) per reference
        bihn[tq]  = b_ih[128 + jn] * (2.0f * LOG2E);
    }

    // ---- loop-invariant LDS offsets (swizzle folded) ----
    const int eS0 = c * 64 + (((g4 * 8) + 0)  ^ ((c & 7) << 3));  // k-step 0
    const int eS1 = c * 64 + (((g4 * 8) + 32) ^ ((c & 7) << 3));  // k-step 1
    const int bytesS0 = eS0 * 2;
    const int bytesS1 = eS1 * 2;
    const _Float16* aA0 = &hst[wave * 2 + 0][eS0];
    const _Float16* aA1 = &hst[wave * 2 + 0][eS1];
    const _Float16* aB0 = &hst[wave * 2 + 1][eS0];
    const _Float16* aB1 = &hst[wave * 2 + 1][eS1];
    _Float16* wr[2][4];
#pragma unroll
    for (int s = 0; s < 2; ++s)
#pragma unroll
        for (int reg = 0; reg < 4; ++reg) {
            int row = g4 * 4 + reg;
            wr[s][reg] = &hst[wave * 2 + s][row * 64 + ((c * 4) ^ ((row & 7) << 3))];
        }

    const f32x4 zero4 = (f32x4){0.0f, 0.0f, 0.0f, 0.0f};

    f32x4 accr[2][4], accz[2][4], accn[2][4];   // zero needed for the t=0 gates
#pragma unroll
    for (int s = 0; s < 2; ++s)
#pragma unroll
        for (int tq = 0; tq < 4; ++tq) {
            accr[s][tq] = zero4;
            accz[s][tq] = zero4;
            accn[s][tq] = zero4;
        }

    float h[2][4][4];  // fp32 h, C layout per stream
#pragma unroll
    for (int s = 0; s < 2; ++s)
#pragma unroll
        for (int tq = 0; tq < 4; ++tq)
#pragma unroll
            for (int reg = 0; reg < 4; ++reg) h[s][tq][reg] = 0.0f;

    const char* wbase = (const char*)&wlds[0];

    // ---- software-pipelined recurrence: streams offset by half a timestep.
    // Schedule per iter t: MFMA_B(t) | gates_A(t) | MFMA_A(t+1) | gates_B(t)
    // -> every MFMA block is followed by ~1600 cyc of independent gate VALU.
    GATES(0, 0);                       // t=0, acc=0 (pure bias+x path)
    MFMA_BLOCK(0, aA0, aA1);           // MFMA_A(1) <- h_A(0)
    GATES(1, 0);

#pragma unroll 1
    for (int t = 1; t < T_STEPS - 1; ++t) {
        MFMA_BLOCK(1, aB0, aB1);       // MFMA_B(t) <- h_B(t-1)
        HAZPAD();
        GATES(0, t);                   // uses MFMA_A(t), issued one phase ago
        MFMA_BLOCK(0, aA0, aA1);       // MFMA_A(t+1) <- h_A(t) just written
        HAZPAD();
        GATES(1, t);                   // uses MFMA_B(t) from top of iter
    }
    // t = 14 epilogue (no MFMA_A(15))
    MFMA_BLOCK(1, aB0, aB1);
    HAZPAD();
    GATES(0, T_STEPS - 1);
    GATES(1, T_STEPS - 1);

    // ---- FC head from exact fp32 h; launder pointers so W_fc/b_fc loads
    // can't be hoisted above the t-loop ----
    const float* wfc = W_fc;
    const float* bfc = b_fc;
    asm volatile("" : "+v"(wfc), "+v"(bfc));
    float wfc0[4], wfc1[4];
#pragma unroll
    for (int tq = 0; tq < 4; ++tq) {
        wfc0[tq] = wfc[tq * 16 + c];
        wfc1[tq] = wfc[64 + tq * 16 + c];
    }
#pragma unroll
    for (int s = 0; s < 2; ++s)
#pragma unroll
    for (int reg = 0; reg < 4; ++reg) {
        float s0 = 0.0f, s1 = 0.0f;
#pragma unroll
        for (int tq = 0; tq < 4; ++tq) {
            s0 = __builtin_fmaf(h[s][tq][reg], wfc0[tq], s0);
            s1 = __builtin_fmaf(h[s][tq][reg], wfc1[tq], s1);
        }
#pragma unroll
        for (int m = 1; m < 16; m <<= 1) {
            s0 += __shfl_xor(s0, m, 64);
            s1 += __shfl_xor(s1, m, 64);
        }
        if (c == 0) {
            int gr = r0 + wave * 32 + s * 16 + g4 * 4 + reg;
            out[gr * 2 + 0] = s0 + bfc[0];
            out[gr * 2 + 1] = s1 + bfc[1];
        }
    }
}

extern "C" void kernel_launch(void* const* d_in, const int* in_sizes, int n_in,
                              void* d_out, int out_size, void* d_ws, size_t ws_size,
                              hipStream_t stream) {
    const float* x    = (const float*)d_in[0];
    const float* W_ih = (const float*)d_in[1];
    const float* W_hh = (const float*)d_in[2];
    const float* b_ih = (const float*)d_in[3];
    const float* b_hh = (const float*)d_in[4];
    const float* W_fc = (const float*)d_in[5];
    const float* b_fc = (const float*)d_in[6];
    float* out = (float*)d_out;

    dim3 grid(B_TOTAL / ROWS_PER_BLOCK);
    dim3 block(256);
    gru_mfma_kernel<<<grid, block, 0, stream>>>(x, W_ih, W_hh, b_ih, b_hh, W_fc, b_fc, out);
}

// Round 10
// 200.581 us; speedup vs baseline: 3.1086x; 1.0396x over previous
//
#include <hip/hip_runtime.h>

#define T_STEPS 15
#define ROWS_PER_BLOCK 128
#define B_TOTAL 262144
#define LOG2E 1.4426950408889634f

typedef _Float16 half8 __attribute__((ext_vector_type(8)));
typedef _Float16 half4 __attribute__((ext_vector_type(4)));
typedef __fp16   fp16x2 __attribute__((ext_vector_type(2)));   // cvt_pkrtz return type
typedef float f32x4 __attribute__((ext_vector_type(4)));

// VGPR-form MFMA (gfx950 unified RF). INIT overwrites acc (C = shared zero
// tuple); "=&v" early-clobber so D can't alias C.
#define MFMA_INIT(acc, a, b, cz) \
    asm("v_mfma_f32_16x16x32_f16 %0, %1, %2, %3" : "=&v"(acc) : "v"(a), "v"(b), "v"(cz))
#define MFMA_ACC(acc, a, b) \
    asm("v_mfma_f32_16x16x32_f16 %0, %1, %2, %0" : "+v"(acc) : "v"(a), "v"(b))

#define SB() __builtin_amdgcn_sched_barrier(0)

// Swizzled element index into a [rows][64] fp16 LDS tile (T2 pattern).
__device__ __forceinline__ int swz(int row, int e) {
    return (row * 64 + e) ^ ((row & 7) << 3);
}

// One gate evaluation (5 trans ops) for (stream SG, quadrant TQ, C-reg RG).
#define GEVAL(SG, RG, TQ, XT) do { \
    float pr = accr[SG][TQ][RG] + __builtin_fmaf(XT, wihr[TQ], sr[TQ]); \
    float er = __builtin_amdgcn_exp2f(-pr); \
    float rg_ = __builtin_amdgcn_rcpf(1.0f + er); \
    float pz = accz[SG][TQ][RG] + __builtin_fmaf(XT, wihz[TQ], sz[TQ]); \
    float ez = __builtin_amdgcn_exp2f(-pz); \
    float na = __builtin_fmaf(rg_, accn[SG][TQ][RG], \
                __builtin_fmaf(rg_, seedn[TQ], \
                 __builtin_fmaf(XT, wihn[TQ], bihn[TQ]))); \
    float en = __builtin_amdgcn_exp2f(-na); \
    float A_ = 1.0f + en; \
    float C_ = 1.0f + ez; \
    float R_ = __builtin_amdgcn_rcpf(A_ * C_); \
    float P_ = __builtin_fmaf(-en, ez, ez); \
    float hn = __builtin_fmaf(h[SG][TQ][RG], A_, P_) * R_; \
    h[SG][TQ][RG] = hn; \
    hnv[TQ] = hn; \
} while (0)

#define PACKWRITE(SG, RG) do { \
    fp16x2 h01 = __builtin_amdgcn_cvt_pkrtz(hnv[0], hnv[1]); \
    fp16x2 h23 = __builtin_amdgcn_cvt_pkrtz(hnv[2], hnv[3]); \
    half4 vh; \
    vh[0] = (_Float16)h01[0]; vh[1] = (_Float16)h01[1]; \
    vh[2] = (_Float16)h23[0]; vh[3] = (_Float16)h23[1]; \
    *(half4*)wr[SG][RG] = vh; \
} while (0)

// Load the 6 B-fragments (r,z,n x 2 k-steps) for quadrant KK.
#define LD6(buf, KK) do { \
    buf[0] = *(const half8*)(bp0 + (KK) * 2048); \
    buf[1] = *(const half8*)(bp1 + (KK) * 2048); \
    buf[2] = *(const half8*)(bp0 + (4 + (KK)) * 2048); \
    buf[3] = *(const half8*)(bp1 + (4 + (KK)) * 2048); \
    buf[4] = *(const half8*)(bp0 + (8 + (KK)) * 2048); \
    buf[5] = *(const half8*)(bp1 + (8 + (KK)) * 2048); \
} while (0)

// Fused chunk: stream-SM MFMA quadrant K interleaved with stream-SG gates
// reg K. PREF issues next chunk's B-frag loads (latency hidden under gates).
// The gate slices (~200 cyc each) separate INIT->ACC (MFMA latency) and
// ds_read->use (LDS latency) by construction; SB() pins the interleave.
#define CHUNK(SM, SG, K, BCUR, PREF) do { \
    float hnv[4]; \
    float XT = xt4[K]; \
    PREF; \
    SB(); \
    MFMA_INIT(accr[SM][K], A0, BCUR[0], zero4); \
    MFMA_INIT(accz[SM][K], A0, BCUR[2], zero4); \
    MFMA_INIT(accn[SM][K], A0, BCUR[4], zero4); \
    SB(); \
    GEVAL(SG, K, 0, XT); GEVAL(SG, K, 1, XT); \
    SB(); \
    MFMA_ACC(accr[SM][K], A1, BCUR[1]); \
    MFMA_ACC(accz[SM][K], A1, BCUR[3]); \
    MFMA_ACC(accn[SM][K], A1, BCUR[5]); \
    SB(); \
    GEVAL(SG, K, 2, XT); GEVAL(SG, K, 3, XT); \
    PACKWRITE(SG, K); \
    SB(); \
} while (0)

// Fused phase: full K=64 matvec for stream SM (24 MFMAs) overlapped with the
// full gate pass for stream SG at timestep TT (16 evals).
#define FUSED(SM, SG, TT) do { \
    int ofA = bytesS0, ofB = bytesS1; \
    asm volatile("" : "+v"(ofA), "+v"(ofB)); \
    const char* bp0 = wbase + ofA; \
    const char* bp1 = wbase + ofB; \
    half8 A0 = *(const half8*)((SM) ? aB0 : aA0); \
    half8 A1 = *(const half8*)((SM) ? aB1 : aA1); \
    f32x4 xt4 = *(const f32x4*)&xlds[(TT) * ROWS_PER_BLOCK + wave * 32 + (SG) * 16 + g4 * 4]; \
    half8 Bf0[6], Bf1[6]; \
    LD6(Bf0, 0); \
    CHUNK(SM, SG, 0, Bf0, LD6(Bf1, 1)); \
    CHUNK(SM, SG, 1, Bf1, LD6(Bf0, 2)); \
    CHUNK(SM, SG, 2, Bf0, LD6(Bf1, 3)); \
    CHUNK(SM, SG, 3, Bf1, (void)0); \
} while (0)

// Plain gate pass (prologue/epilogue ends of the software pipeline).
#define GATES_PLAIN(SG, TT) do { \
    f32x4 xt4 = *(const f32x4*)&xlds[(TT) * ROWS_PER_BLOCK + wave * 32 + (SG) * 16 + g4 * 4]; \
    _Pragma("unroll") \
    for (int rg2 = 0; rg2 < 4; ++rg2) { \
        float hnv[4]; \
        float XT = xt4[rg2]; \
        GEVAL(SG, rg2, 0, XT); GEVAL(SG, rg2, 1, XT); \
        GEVAL(SG, rg2, 2, XT); GEVAL(SG, rg2, 3, XT); \
        PACKWRITE(SG, rg2); \
    } \
} while (0)

__global__ __launch_bounds__(256, 2) void gru_mfma_kernel(
    const float* __restrict__ x,     // (B,15)
    const float* __restrict__ W_ih,  // (192,1)
    const float* __restrict__ W_hh,  // (192,64)
    const float* __restrict__ b_ih,  // (192,)
    const float* __restrict__ b_hh,  // (192,)
    const float* __restrict__ W_fc,  // (2,64)
    const float* __restrict__ b_fc,  // (2,)
    float* __restrict__ out)         // (B,2)
{
    __shared__ _Float16 wlds[192 * 64];                 // 24576 B, exp2-prescaled W_hh^T
    __shared__ float    xlds[T_STEPS * ROWS_PER_BLOCK]; // 7680 B, [t][row]
    __shared__ _Float16 hst[8][16 * 64];                // [wave*2+stream], 16384 B

    const int tid  = threadIdx.x;
    const int wave = tid >> 6;
    const int lane = tid & 63;
    const int c    = lane & 15;   // N-col / A-row index
    const int g4   = lane >> 4;   // k-slot group / C-row group
    const int r0   = blockIdx.x * ROWS_PER_BLOCK;

    // ---- stage B = W_hh^T, k-permuted by invs(s)=(s&3)*16+(s>>2), exp2-scaled ----
    for (int idx = tid; idx < 192 * 64; idx += 256) {
        int n = idx >> 6, s = idx & 63;
        int korig = (s & 3) * 16 + (s >> 2);
        float scale = (n < 128) ? LOG2E : (2.0f * LOG2E);
        wlds[swz(n, s)] = (_Float16)(W_hh[n * 64 + korig] * scale);
    }
    // x transposed: xlds[t*128 + row]
    for (int idx = tid; idx < ROWS_PER_BLOCK * T_STEPS; idx += 256) {
        int row = idx / T_STEPS, t = idx - row * T_STEPS;
        xlds[t * ROWS_PER_BLOCK + row] = x[r0 * T_STEPS + idx];
    }
    __syncthreads();

    // ---- per-lane gate constants (jn = tq*16 + c), exp2-prescaled ----
    float wihr[4], wihz[4], wihn[4], sr[4], sz[4], seedn[4], bihn[4];
#pragma unroll
    for (int tq = 0; tq < 4; ++tq) {
        int jn = tq * 16 + c;
        wihr[tq]  = W_ih[jn] * LOG2E;
        wihz[tq]  = W_ih[64 + jn] * LOG2E;
        wihn[tq]  = W_ih[128 + jn] * (2.0f * LOG2E);
        sr[tq]    = (b_ih[jn] + b_hh[jn]) * LOG2E;
        sz[tq]    = (b_ih[64 + jn] + b_hh[64 + jn]) * LOG2E;
        seedn[tq] = b_hh[128 + jn] * (2.0f * LOG2E);  // stays inside r*(.) per reference
        bihn[tq]  = b_ih[128 + jn] * (2.0f * LOG2E);
    }

    // ---- loop-invariant LDS offsets (swizzle folded) ----
    const int eS0 = c * 64 + (((g4 * 8) + 0)  ^ ((c & 7) << 3));  // k-step 0
    const int eS1 = c * 64 + (((g4 * 8) + 32) ^ ((c & 7) << 3));  // k-step 1
    const int bytesS0 = eS0 * 2;
    const int bytesS1 = eS1 * 2;
    const _Float16* aA0 = &hst[wave * 2 + 0][eS0];
    const _Float16* aA1 = &hst[wave * 2 + 0][eS1];
    const _Float16* aB0 = &hst[wave * 2 + 1][eS0];
    const _Float16* aB1 = &hst[wave * 2 + 1][eS1];
    _Float16* wr[2][4];
#pragma unroll
    for (int s = 0; s < 2; ++s)
#pragma unroll
        for (int reg = 0; reg < 4; ++reg) {
            int row = g4 * 4 + reg;
            wr[s][reg] = &hst[wave * 2 + s][row * 64 + ((c * 4) ^ ((row & 7) << 3))];
        }

    const f32x4 zero4 = (f32x4){0.0f, 0.0f, 0.0f, 0.0f};

    f32x4 accr[2][4], accz[2][4], accn[2][4];   // zero needed for the t=0 gates
#pragma unroll
    for (int s = 0; s < 2; ++s)
#pragma unroll
        for (int tq = 0; tq < 4; ++tq) {
            accr[s][tq] = zero4;
            accz[s][tq] = zero4;
            accn[s][tq] = zero4;
        }

    float h[2][4][4];  // fp32 h, C layout per stream
#pragma unroll
    for (int s = 0; s < 2; ++s)
#pragma unroll
        for (int tq = 0; tq < 4; ++tq)
#pragma unroll
            for (int reg = 0; reg < 4; ++reg) h[s][tq][reg] = 0.0f;

    const char* wbase = (const char*)&wlds[0];

    // ---- software pipeline, chunk-fused:
    // gA(0) | F(MA(1) x gB(0)) | { F(MB(t) x gA(t)); F(MA(t+1) x gB(t)) }  t=1..13
    //      | F(MB(14) x gA(14)) | gB(14)
    GATES_PLAIN(0, 0);            // h_A(0), acc=0 path
    FUSED(0, 1, 0);               // MFMA_A(1) <- h_A(0);  gates_B(0) acc=0

#pragma unroll 1
    for (int t = 1; t < T_STEPS - 1; ++t) {
        FUSED(1, 0, t);           // MFMA_B(t) <- h_B(t-1);  gates_A(t) <- MFMA_A(t)
        FUSED(0, 1, t);           // MFMA_A(t+1) <- h_A(t);  gates_B(t) <- MFMA_B(t)
    }

    FUSED(1, 0, T_STEPS - 1);     // MFMA_B(14); gates_A(14)
    // pad: gates_B(14) reads chunk-3 accs written ~200 cyc upstream (insurance)
    SB(); asm volatile("s_nop 7"); SB();
    GATES_PLAIN(1, T_STEPS - 1);  // gates_B(14) <- MFMA_B(14)

    // ---- FC head from exact fp32 h; launder pointers so W_fc/b_fc loads
    // can't be hoisted above the t-loop ----
    const float* wfc = W_fc;
    const float* bfc = b_fc;
    asm volatile("" : "+v"(wfc), "+v"(bfc));
    float wfc0[4], wfc1[4];
#pragma unroll
    for (int tq = 0; tq < 4; ++tq) {
        wfc0[tq] = wfc[tq * 16 + c];
        wfc1[tq] = wfc[64 + tq * 16 + c];
    }
#pragma unroll
    for (int s = 0; s < 2; ++s)
#pragma unroll
    for (int reg = 0; reg < 4; ++reg) {
        float s0 = 0.0f, s1 = 0.0f;
#pragma unroll
        for (int tq = 0; tq < 4; ++tq) {
            s0 = __builtin_fmaf(h[s][tq][reg], wfc0[tq], s0);
            s1 = __builtin_fmaf(h[s][tq][reg], wfc1[tq], s1);
        }
#pragma unroll
        for (int m = 1; m < 16; m <<= 1) {
            s0 += __shfl_xor(s0, m, 64);
            s1 += __shfl_xor(s1, m, 64);
        }
        if (c == 0) {
            int gr = r0 + wave * 32 + s * 16 + g4 * 4 + reg;
            out[gr * 2 + 0] = s0 + bfc[0];
            out[gr * 2 + 1] = s1 + bfc[1];
        }
    }
}

extern "C" void kernel_launch(void* const* d_in, const int* in_sizes, int n_in,
                              void* d_out, int out_size, void* d_ws, size_t ws_size,
                              hipStream_t stream) {
    const float* x    = (const float*)d_in[0];
    const float* W_ih = (const float*)d_in[1];
    const float* W_hh = (const float*)d_in[2];
    const float* b_ih = (const float*)d_in[3];
    const float* b_hh = (const float*)d_in[4];
    const float* W_fc = (const float*)d_in[5];
    const float* b_fc = (const float*)d_in[6];
    float* out = (float*)d_out;

    dim3 grid(B_TOTAL / ROWS_PER_BLOCK);
    dim3 block(256);
    gru_mfma_kernel<<<grid, block, 0, stream>>>(x, W_ih, W_hh, b_ih, b_hh, W_fc, b_fc, out);
}